// Round 1
// 251.086 us; speedup vs baseline: 1.0381x; 1.0381x over previous
//
#include <hip/hip_runtime.h>
#include <hip/hip_fp16.h>

#define N_NODES 100000
#define N_EDGES 1600000
#define IN_F 128
#define OUT_F 32
#define HEADS 2
#define HO 64  // HEADS*OUT_F

#define NBUCK 782           // bucket = dst >> 7 (128-node slices)
#define BIN_BLOCKS 200
#define BIN_THREADS 1024
#define EPB (N_EDGES / BIN_BLOCKS)   // 8000 edges per bin block
#define CAP 36              // per (block,bucket): mean 10.2, sigma 3.2, +8 sigma
#define LCAP 2368           // per-bucket edge capacity: mean 2046, sigma 45, +7.1 sigma

// feat = x @ W (N x 128 @ 128 x 64) -> fp16, fused el/er. Conflict-audited (R4).
// Block 0 additionally folds the MLP: wcomb = W1@W2, ccomb = b1.W2+b2.
__global__ void feat_k(const float* __restrict__ x, const float* __restrict__ W,
                       const float* __restrict__ attn_l, const float* __restrict__ attn_r,
                       __half* __restrict__ feat16, float* __restrict__ el, float* __restrict__ er,
                       const float* __restrict__ W1, const float* __restrict__ b1,
                       const float* __restrict__ W2, const float* __restrict__ b2,
                       float* __restrict__ wcomb, float* __restrict__ ccomb){
  __shared__ __align__(16) float Ws[IN_F*HO];   // 32 KB
  __shared__ __align__(16) float xs[64*132];    // 33.8 KB
  int tid = threadIdx.x;
  if (blockIdx.x == 0){
    if (tid < HO){
      float a = 0.f;
      for (int k = 0; k < OUT_F; ++k) a = fmaf(W1[tid*OUT_F + k], W2[k], a);
      wcomb[tid] = a;
    }
    if (tid == HO){
      float a = 0.f;
      for (int k = 0; k < OUT_F; ++k) a = fmaf(b1[k], W2[k], a);
      *ccomb = a + b2[0];
    }
  }
  int node0 = blockIdx.x*64;
  for (int i = tid; i < 2048; i += 256)
    ((float4*)Ws)[i] = ((const float4*)W)[i];
  for (int i = tid; i < 2048; i += 256){
    int ln = i >> 5, kq = i & 31;
    int n = node0 + ln;
    float4 v = (n < N_NODES) ? ((const float4*)x)[(size_t)n*32 + kq]
                             : make_float4(0.f,0.f,0.f,0.f);
    *(float4*)&xs[ln*132 + kq*4] = v;
  }
  __syncthreads();

  int nq = tid >> 4, cq = tid & 15;
  int n0 = nq*4, c0 = cq*4;
  float acc[4][4] = {{0.f,0.f,0.f,0.f},{0.f,0.f,0.f,0.f},{0.f,0.f,0.f,0.f},{0.f,0.f,0.f,0.f}};

  for (int k = 0; k < IN_F; k += 4){
    float xk[4][4];
    #pragma unroll
    for (int j = 0; j < 4; ++j){
      float4 t = *(const float4*)&xs[(n0+j)*132 + k];
      xk[j][0]=t.x; xk[j][1]=t.y; xk[j][2]=t.z; xk[j][3]=t.w;
    }
    #pragma unroll
    for (int d = 0; d < 4; ++d){
      float4 w4 = *(const float4*)&Ws[(k+d)*HO + c0];
      #pragma unroll
      for (int j = 0; j < 4; ++j){
        acc[j][0] = fmaf(xk[j][d], w4.x, acc[j][0]);
        acc[j][1] = fmaf(xk[j][d], w4.y, acc[j][1]);
        acc[j][2] = fmaf(xk[j][d], w4.z, acc[j][2]);
        acc[j][3] = fmaf(xk[j][d], w4.w, acc[j][3]);
      }
    }
  }

  float4 al4 = *(const float4*)&attn_l[c0];
  float4 ar4 = *(const float4*)&attn_r[c0];
  #pragma unroll
  for (int j = 0; j < 4; ++j){
    int n = node0 + n0 + j;
    float p = acc[j][0]*al4.x + acc[j][1]*al4.y + acc[j][2]*al4.z + acc[j][3]*al4.w;
    float q = acc[j][0]*ar4.x + acc[j][1]*ar4.y + acc[j][2]*ar4.z + acc[j][3]*ar4.w;
    #pragma unroll
    for (int off = 4; off; off >>= 1){ p += __shfl_xor(p, off); q += __shfl_xor(q, off); }
    if (n < N_NODES){
      __half2 h01 = __float22half2_rn(make_float2(acc[j][0], acc[j][1]));
      __half2 h23 = __float22half2_rn(make_float2(acc[j][2], acc[j][3]));
      union { uint2 u; __half2 h[2]; } pk; pk.h[0]=h01; pk.h[1]=h23;
      *(uint2*)&feat16[(size_t)n*HO + c0] = pk.u;
      if ((cq & 7) == 0){
        int h = cq >> 3;
        el[n*HEADS + h] = p;
        er[n*HEADS + h] = q;
      }
    }
  }
}

// Phase 1: bucket edges by dst>>7, ex = exp(leaky(el[s]+er[d])) (fp16x2).
// 200 blocks x 1024 threads: per-block touched staging ~100 KB -> L2-absorbed.
__global__ void bin_k(const int* __restrict__ src, const int* __restrict__ dst,
                      const float* __restrict__ el, const float* __restrict__ er,
                      int* __restrict__ counts, uint2* __restrict__ stg){
  __shared__ int cnt[NBUCK];
  int tid = threadIdx.x, blk = blockIdx.x;
  for (int i = tid; i < NBUCK; i += BIN_THREADS) cnt[i] = 0;
  __syncthreads();
  const int4* s4p = (const int4*)(src + blk*EPB);
  const int4* d4p = (const int4*)(dst + blk*EPB);
  for (int i = tid; i < EPB/4; i += BIN_THREADS){
    int4 s4 = s4p[i];
    int4 d4 = d4p[i];
    int ss[4] = {s4.x, s4.y, s4.z, s4.w};
    int dd[4] = {d4.x, d4.y, d4.z, d4.w};
    #pragma unroll
    for (int u = 0; u < 4; ++u){
      int s = ss[u], d = dd[u];
      float2 elv = *(const float2*)&el[s*HEADS];
      float2 erv = *(const float2*)&er[d*HEADS];
      float t0 = elv.x + erv.x, t1 = elv.y + erv.y;
      t0 = t0 > 0.f ? t0 : 0.2f*t0;
      t1 = t1 > 0.f ? t1 : 0.2f*t1;
      __half2 ex2 = __float22half2_rn(make_float2(__expf(t0), __expf(t1)));
      int b = d >> 7;
      int slot = atomicAdd(&cnt[b], 1);
      if (slot < CAP)
        stg[((size_t)blk*NBUCK + b)*CAP + slot] =
          make_uint2(((unsigned int)s << 7) | (unsigned int)(d & 127),
                     *(const unsigned int*)&ex2);
    }
  }
  __syncthreads();
  for (int i = tid; i < NBUCK; i += BIN_THREADS)
    counts[blk*NBUCK + i] = cnt[i] < CAP ? cnt[i] : CAP;
}

// Fused scatter + aggregate, v2:
//  - sweep 1 reads only the 4B key of each staged record -> LDS histogram
//  - scan -> start/cur
//  - sweep 2 re-reads stg (L2-hot) and places records directly sorted (no raw list)
//  - softmax denominator is accumulated IN the aggregate loop (deferred divide),
//    so pass 1 has no dsum atomics and the alpha multiply leaves the inner loop.
// LDS: 18.5 KB lsev + 1.5 KB hist/start/cur  (was 40 KB) -> no LDS occupancy cap.
__global__ void __launch_bounds__(512, 8) scatter_agg_k(
                              const int* __restrict__ counts, const uint2* __restrict__ stg,
                              const __half* __restrict__ feat16, const float* __restrict__ bias,
                              const float* __restrict__ wcomb,
                              float* __restrict__ s1, float* __restrict__ s2){
  __shared__ uint2 lsev[LCAP];       // 18.5 KB
  __shared__ int hist[128];
  __shared__ int start[128];
  __shared__ int cur[128];
  __shared__ int wtot[2];
  int b = blockIdx.x;
  int tid = threadIdx.x;
  int w = tid >> 6, lane = tid & 63;
  if (tid < 128) hist[tid] = 0;
  __syncthreads();

  int grp = tid >> 3, gl = tid & 7;
  // sweep 1: histogram of local dst (key dword only; lines get L2-warm here)
  for (int blk = grp; blk < BIN_BLOCKS; blk += 64){
    int n = counts[blk*NBUCK + b];
    const unsigned int* segx = (const unsigned int*)(stg + ((size_t)blk*NBUCK + b)*CAP);
    for (int j = gl; j < n; j += 8){
      unsigned int rx = segx[2*j];
      atomicAdd(&hist[rx & 127], 1);
    }
  }
  __syncthreads();

  // exclusive scan of hist[128] (2 waves)
  int v = 0, inc = 0;
  if (tid < 128){
    v = hist[tid];
    inc = v;
    #pragma unroll
    for (int off = 1; off < 64; off <<= 1){
      int t = __shfl_up(inc, off);
      if (lane >= off) inc += t;
    }
    if (lane == 63) wtot[w] = inc;
  }
  __syncthreads();
  if (tid == 0){ int t0 = wtot[0]; wtot[0] = 0; wtot[1] = t0; }
  __syncthreads();
  if (tid < 128){
    int excl = wtot[w] + inc - v;
    start[tid] = excl;
    cur[tid] = excl;
  }
  __syncthreads();

  // sweep 2: direct sorted placement (stg re-read hits L2)
  for (int blk = grp; blk < BIN_BLOCKS; blk += 64){
    int n = counts[blk*NBUCK + b];
    const uint2* seg = stg + ((size_t)blk*NBUCK + b)*CAP;
    for (int j = gl; j < n; j += 8){
      uint2 r = seg[j];
      int pos = atomicAdd(&cur[r.x & 127], 1);
      if (pos < LCAP) lsev[pos] = make_uint2(r.x >> 7, r.y);
    }
  }
  __syncthreads();

  // aggregate: wave w handles local nodes w*16 .. w*16+15; 16 edges in flight.
  int g  = lane >> 4;
  int c4 = lane & 15;
  int h  = (c4 >= 8);
  float b0v = bias[c4*4 + 0], b1v = bias[c4*4 + 1], b2v = bias[c4*4 + 2], b3v = bias[c4*4 + 3];
  int f0 = (c4 & 7)*4;
  int wo = (h ? 32 : 0) + f0;   // lanes c4<8 compute MLP row 0 (s1), c4>=8 row 1 (s2)
  float m0 = wcomb[wo], m1 = wcomb[wo+1], m2 = wcomb[wo+2], m3 = wcomb[wo+3];
  for (int i = 0; i < 16; ++i){
    int nl = w*16 + i;
    int node = (b << 7) + nl;
    if (node >= N_NODES) break;
    int s0 = start[nl];
    int e0 = cur[nl]; if (e0 > LCAP) e0 = LCAP;
    int deg = e0 - s0; if (deg < 0) deg = 0;

    float a0=0.f, a1=0.f, a2=0.f, a3=0.f, dn=0.f;
    for (int j0 = 0; j0 < deg; j0 += 16){
      int jA = j0 + g, jB = j0 + 4 + g, jC = j0 + 8 + g, jD = j0 + 12 + g;
      float alA=0.f, alB=0.f, alC=0.f, alD=0.f;
      int snA=0, snB=0, snC=0, snD=0;
      if (jA < deg){ uint2 r = lsev[s0+jA]; snA = r.x;
        float2 e = __half22float2(*(const __half2*)&r.y); alA = (h?e.y:e.x); }
      if (jB < deg){ uint2 r = lsev[s0+jB]; snB = r.x;
        float2 e = __half22float2(*(const __half2*)&r.y); alB = (h?e.y:e.x); }
      if (jC < deg){ uint2 r = lsev[s0+jC]; snC = r.x;
        float2 e = __half22float2(*(const __half2*)&r.y); alC = (h?e.y:e.x); }
      if (jD < deg){ uint2 r = lsev[s0+jD]; snD = r.x;
        float2 e = __half22float2(*(const __half2*)&r.y); alD = (h?e.y:e.x); }
      dn += alA + alB + alC + alD;
      uint2 vA = *(const uint2*)(feat16 + (size_t)snA*HO + c4*4);
      uint2 vB = *(const uint2*)(feat16 + (size_t)snB*HO + c4*4);
      uint2 vC = *(const uint2*)(feat16 + (size_t)snC*HO + c4*4);
      uint2 vD = *(const uint2*)(feat16 + (size_t)snD*HO + c4*4);
      float2 fA01 = __half22float2(*(const __half2*)&vA.x);
      float2 fA23 = __half22float2(*(const __half2*)&vA.y);
      float2 fB01 = __half22float2(*(const __half2*)&vB.x);
      float2 fB23 = __half22float2(*(const __half2*)&vB.y);
      float2 fC01 = __half22float2(*(const __half2*)&vC.x);
      float2 fC23 = __half22float2(*(const __half2*)&vC.y);
      float2 fD01 = __half22float2(*(const __half2*)&vD.x);
      float2 fD23 = __half22float2(*(const __half2*)&vD.y);
      a0 = fmaf(alA, fA01.x, a0); a0 = fmaf(alB, fB01.x, a0);
      a0 = fmaf(alC, fC01.x, a0); a0 = fmaf(alD, fD01.x, a0);
      a1 = fmaf(alA, fA01.y, a1); a1 = fmaf(alB, fB01.y, a1);
      a1 = fmaf(alC, fC01.y, a1); a1 = fmaf(alD, fD01.y, a1);
      a2 = fmaf(alA, fA23.x, a2); a2 = fmaf(alB, fB23.x, a2);
      a2 = fmaf(alC, fC23.x, a2); a2 = fmaf(alD, fD23.x, a2);
      a3 = fmaf(alA, fA23.y, a3); a3 = fmaf(alB, fB23.y, a3);
      a3 = fmaf(alC, fC23.y, a3); a3 = fmaf(alD, fD23.y, a3);
    }
    a0 += __shfl_xor(a0, 16); a1 += __shfl_xor(a1, 16);
    a2 += __shfl_xor(a2, 16); a3 += __shfl_xor(a3, 16);
    dn += __shfl_xor(dn, 16);
    a0 += __shfl_xor(a0, 32); a1 += __shfl_xor(a1, 32);
    a2 += __shfl_xor(a2, 32); a3 += __shfl_xor(a3, 32);
    dn += __shfl_xor(dn, 32);
    float rh = dn > 0.f ? 1.f/dn : 0.f;   // deferred softmax divide
    a0 = fmaf(a0, rh, b0v); a1 = fmaf(a1, rh, b1v);
    a2 = fmaf(a2, rh, b2v); a3 = fmaf(a3, rh, b3v);
    float h0 = 0.5f*(a0 + __shfl_xor(a0, 8)); h0 = fmaxf(h0, 0.f);
    float h1 = 0.5f*(a1 + __shfl_xor(a1, 8)); h1 = fmaxf(h1, 0.f);
    float h2 = 0.5f*(a2 + __shfl_xor(a2, 8)); h2 = fmaxf(h2, 0.f);
    float h3 = 0.5f*(a3 + __shfl_xor(a3, 8)); h3 = fmaxf(h3, 0.f);
    float r = h0*m0 + h1*m1 + h2*m2 + h3*m3;
    r += __shfl_xor(r, 4); r += __shfl_xor(r, 2); r += __shfl_xor(r, 1);
    if (lane == 0)      s1[node] = r;
    else if (lane == 8) s2[node] = r;
  }
}

__global__ void edge_score_k(const int* __restrict__ src, const int* __restrict__ dst,
                             const float* __restrict__ s1, const float* __restrict__ s2,
                             const float* __restrict__ ccomb, float* __restrict__ out){
  int i = blockIdx.x*blockDim.x + threadIdx.x;
  if (i >= N_EDGES/4) return;
  int4 s4 = ((const int4*)src)[i];
  int4 d4 = ((const int4*)dst)[i];
  float c = ccomb[0];
  float4 o;
  o.x = s1[s4.x] + s2[d4.x] + c;
  o.y = s1[s4.y] + s2[d4.y] + c;
  o.z = s1[s4.z] + s2[d4.z] + c;
  o.w = s1[s4.w] + s2[d4.w] + c;
  ((float4*)out)[i] = o;
}

extern "C" void kernel_launch(void* const* d_in, const int* in_sizes, int n_in,
                              void* d_out, int out_size, void* d_ws, size_t ws_size,
                              hipStream_t stream){
  const float* x      = (const float*)d_in[0];
  const float* W      = (const float*)d_in[1];
  const float* attn_l = (const float*)d_in[2];
  const float* attn_r = (const float*)d_in[3];
  const float* bias   = (const float*)d_in[4];
  const float* W1     = (const float*)d_in[5];
  const float* b1     = (const float*)d_in[6];
  const float* W2     = (const float*)d_in[7];
  const float* b2     = (const float*)d_in[8];
  const int*   src    = (const int*)d_in[9];
  const int*   dst    = (const int*)d_in[10];
  float* out = (float*)d_out;

  float* ws = (float*)d_ws;
  size_t off = 0;
  __half* feat16 = (__half*)(ws + off); off += (size_t)N_NODES*HO/2;
  float*  el     = ws + off; off += (size_t)N_NODES*HEADS;
  float*  er     = ws + off; off += (size_t)N_NODES*HEADS;
  float*  s1     = ws + off; off += N_NODES;
  float*  s2     = ws + off; off += N_NODES;
  float*  wcomb  = ws + off; off += 64;
  float*  ccomb  = ws + off; off += 64;
  int*    counts = (int*)(ws + off); off += (size_t)BIN_BLOCKS*NBUCK;
  off = (off + 1) & ~(size_t)1;  // 8B align
  uint2*  stg    = (uint2*)(ws + off); off += (size_t)2*BIN_BLOCKS*NBUCK*CAP;

  feat_k<<<(N_NODES + 63)/64, 256, 0, stream>>>(x, W, attn_l, attn_r, feat16, el, er,
                                                W1, b1, W2, b2, wcomb, ccomb);
  bin_k<<<BIN_BLOCKS, BIN_THREADS, 0, stream>>>(src, dst, el, er, counts, stg);
  scatter_agg_k<<<NBUCK, 512, 0, stream>>>(counts, stg, feat16, bias, wcomb, s1, s2);
  edge_score_k<<<(N_EDGES/4 + 255)/256, 256, 0, stream>>>(src, dst, s1, s2, ccomb, out);
}

// Round 2
// 238.055 us; speedup vs baseline: 1.0949x; 1.0547x over previous
//
#include <hip/hip_runtime.h>
#include <hip/hip_fp16.h>

#define N_NODES 100000
#define N_EDGES 1600000
#define IN_F 128
#define OUT_F 32
#define HEADS 2
#define HO 64  // HEADS*OUT_F

#define NBUCK 782           // bucket = dst >> 7 (128-node slices)
#define BIN_BLOCKS 200
#define BIN_THREADS 1024
#define EPB (N_EDGES / BIN_BLOCKS)   // 8000 edges per bin block
#define CAP 36              // per (block,bucket): mean 10.2, sigma 3.2, +8 sigma
#define LCAP 2368           // per-bucket edge capacity: mean 2046, sigma 45, +7.1 sigma

typedef __attribute__((ext_vector_type(8))) _Float16 half8;
typedef __attribute__((ext_vector_type(4))) _Float16 half4v;
typedef __attribute__((ext_vector_type(4))) float    f32x4;

#define XPAD 136   // 128 halves + 8 pad -> 272B row stride: 16B-aligned, 8-bank spread

// One-time prep: Wt16[c][k] = (fp16) W[k][c]  (64 x 128), plus folded MLP:
// wcomb = W1@W2, ccomb = b1.W2 + b2.
__global__ void wprep_k(const float* __restrict__ W,
                        const float* __restrict__ W1, const float* __restrict__ b1,
                        const float* __restrict__ W2, const float* __restrict__ b2,
                        _Float16* __restrict__ Wt16, float* __restrict__ wcomb,
                        float* __restrict__ ccomb){
  int tid = threadIdx.x;
  if (tid < HO){
    float a = 0.f;
    for (int k = 0; k < OUT_F; ++k) a = fmaf(W1[tid*OUT_F + k], W2[k], a);
    wcomb[tid] = a;
  }
  if (tid == HO){
    float a = 0.f;
    for (int k = 0; k < OUT_F; ++k) a = fmaf(b1[k], W2[k], a);
    *ccomb = a + b2[0];
  }
  for (int i = tid; i < 2048; i += 256){
    int k  = i >> 4;          // 0..127
    int c4 = (i & 15) * 4;    // 0..60
    float4 v = ((const float4*)W)[i];
    Wt16[(c4+0)*IN_F + k] = (_Float16)v.x;
    Wt16[(c4+1)*IN_F + k] = (_Float16)v.y;
    Wt16[(c4+2)*IN_F + k] = (_Float16)v.z;
    Wt16[(c4+3)*IN_F + k] = (_Float16)v.w;
  }
}

// feat = x @ W via fp16 MFMA (16x16x32). Block: 256 thr / 4 waves, 64 nodes x 64 cols.
// Wave w: rows 16w..16w+15, 4 col-tiles x 4 k-steps = 16 MFMA, acc fp32.
// el/er fused from accumulators (no feat re-read).
__global__ __launch_bounds__(256) void feat_k(
                       const float* __restrict__ x, const _Float16* __restrict__ Wt16,
                       const float* __restrict__ attn_l, const float* __restrict__ attn_r,
                       __half* __restrict__ feat16, float* __restrict__ el, float* __restrict__ er){
  __shared__ __align__(16) _Float16 Ws[64*XPAD];   // 17.4 KB  (B: Wt[c][k])
  __shared__ __align__(16) _Float16 xs[64*XPAD];   // 17.4 KB  (A: x[n][k] fp16)
  int tid = threadIdx.x;
  int node0 = blockIdx.x*64;

  // stage Wt16 (L2-hot, 16 KB) into padded LDS
  for (int i = tid; i < 2048; i += 256){
    int c = i >> 5, k4 = i & 31;
    *(uint2*)&Ws[c*XPAD + k4*4] = ((const uint2*)Wt16)[i];
  }
  // stage x tile, fp32 -> fp16
  for (int i = tid; i < 2048; i += 256){
    int ln = i >> 5, kq = i & 31;
    int n = node0 + ln;
    float4 v = (n < N_NODES) ? ((const float4*)x)[(size_t)n*32 + kq]
                             : make_float4(0.f,0.f,0.f,0.f);
    half4v hv = { (_Float16)v.x, (_Float16)v.y, (_Float16)v.z, (_Float16)v.w };
    *(half4v*)&xs[ln*XPAD + kq*4] = hv;
  }
  __syncthreads();

  int w = tid >> 6, lane = tid & 63;
  int row_base = w*16;
  int lr = lane & 15, lg = lane >> 4;   // A: row=lr, k-chunk=lg*8 ; B: col=lr
  f32x4 acc0 = {0.f,0.f,0.f,0.f}, acc1 = {0.f,0.f,0.f,0.f};
  f32x4 acc2 = {0.f,0.f,0.f,0.f}, acc3 = {0.f,0.f,0.f,0.f};

  #pragma unroll
  for (int kk = 0; kk < 4; ++kk){
    int ko = kk*32 + lg*8;
    half8 a  = *(const half8*)&xs[(row_base + lr)*XPAD + ko];
    half8 b0 = *(const half8*)&Ws[( 0 + lr)*XPAD + ko];
    half8 b1 = *(const half8*)&Ws[(16 + lr)*XPAD + ko];
    half8 b2 = *(const half8*)&Ws[(32 + lr)*XPAD + ko];
    half8 b3 = *(const half8*)&Ws[(48 + lr)*XPAD + ko];
    acc0 = __builtin_amdgcn_mfma_f32_16x16x32_f16(a, b0, acc0, 0, 0, 0);
    acc1 = __builtin_amdgcn_mfma_f32_16x16x32_f16(a, b1, acc1, 0, 0, 0);
    acc2 = __builtin_amdgcn_mfma_f32_16x16x32_f16(a, b2, acc2, 0, 0, 0);
    acc3 = __builtin_amdgcn_mfma_f32_16x16x32_f16(a, b3, acc3, 0, 0, 0);
  }

  float al0 = attn_l[ 0 + lr], al1 = attn_l[16 + lr];
  float al2 = attn_l[32 + lr], al3 = attn_l[48 + lr];
  float ar0 = attn_r[ 0 + lr], ar1 = attn_r[16 + lr];
  float ar2 = attn_r[32 + lr], ar3 = attn_r[48 + lr];

  #pragma unroll
  for (int r = 0; r < 4; ++r){
    int n = node0 + row_base + lg*4 + r;
    float f0 = acc0[r], f1 = acc1[r], f2 = acc2[r], f3 = acc3[r];
    // per-head attention dot partials (head0 = cols 0..31, head1 = cols 32..63)
    float p0 = f0*al0 + f1*al1, p1 = f2*al2 + f3*al3;
    float q0 = f0*ar0 + f1*ar1, q1 = f2*ar2 + f3*ar3;
    #pragma unroll
    for (int off = 1; off < 16; off <<= 1){
      p0 += __shfl_xor(p0, off); p1 += __shfl_xor(p1, off);
      q0 += __shfl_xor(q0, off); q1 += __shfl_xor(q1, off);
    }
    if (n < N_NODES){
      size_t base = (size_t)n*HO;
      feat16[base +  0 + lr] = __float2half_rn(f0);
      feat16[base + 16 + lr] = __float2half_rn(f1);
      feat16[base + 32 + lr] = __float2half_rn(f2);
      feat16[base + 48 + lr] = __float2half_rn(f3);
      if (lr == 0){
        *(float2*)&el[n*HEADS] = make_float2(p0, p1);
        *(float2*)&er[n*HEADS] = make_float2(q0, q1);
      }
    }
  }
}

// Phase 1: bucket edges by dst>>7, ex = exp(leaky(el[s]+er[d])) (fp16x2).
__global__ void bin_k(const int* __restrict__ src, const int* __restrict__ dst,
                      const float* __restrict__ el, const float* __restrict__ er,
                      int* __restrict__ counts, uint2* __restrict__ stg){
  __shared__ int cnt[NBUCK];
  int tid = threadIdx.x, blk = blockIdx.x;
  for (int i = tid; i < NBUCK; i += BIN_THREADS) cnt[i] = 0;
  __syncthreads();
  const int4* s4p = (const int4*)(src + blk*EPB);
  const int4* d4p = (const int4*)(dst + blk*EPB);
  for (int i = tid; i < EPB/4; i += BIN_THREADS){
    int4 s4 = s4p[i];
    int4 d4 = d4p[i];
    int ss[4] = {s4.x, s4.y, s4.z, s4.w};
    int dd[4] = {d4.x, d4.y, d4.z, d4.w};
    #pragma unroll
    for (int u = 0; u < 4; ++u){
      int s = ss[u], d = dd[u];
      float2 elv = *(const float2*)&el[s*HEADS];
      float2 erv = *(const float2*)&er[d*HEADS];
      float t0 = elv.x + erv.x, t1 = elv.y + erv.y;
      t0 = t0 > 0.f ? t0 : 0.2f*t0;
      t1 = t1 > 0.f ? t1 : 0.2f*t1;
      __half2 ex2 = __float22half2_rn(make_float2(__expf(t0), __expf(t1)));
      int b = d >> 7;
      int slot = atomicAdd(&cnt[b], 1);
      if (slot < CAP)
        stg[((size_t)blk*NBUCK + b)*CAP + slot] =
          make_uint2(((unsigned int)s << 7) | (unsigned int)(d & 127),
                     *(const unsigned int*)&ex2);
    }
  }
  __syncthreads();
  for (int i = tid; i < NBUCK; i += BIN_THREADS)
    counts[blk*NBUCK + i] = cnt[i] < CAP ? cnt[i] : CAP;
}

// Fused scatter + aggregate (v2: two-sweep direct placement, deferred softmax divide).
__global__ void __launch_bounds__(512, 8) scatter_agg_k(
                              const int* __restrict__ counts, const uint2* __restrict__ stg,
                              const __half* __restrict__ feat16, const float* __restrict__ bias,
                              const float* __restrict__ wcomb,
                              float* __restrict__ s1, float* __restrict__ s2){
  __shared__ uint2 lsev[LCAP];       // 18.5 KB
  __shared__ int hist[128];
  __shared__ int start[128];
  __shared__ int cur[128];
  __shared__ int wtot[2];
  int b = blockIdx.x;
  int tid = threadIdx.x;
  int w = tid >> 6, lane = tid & 63;
  if (tid < 128) hist[tid] = 0;
  __syncthreads();

  int grp = tid >> 3, gl = tid & 7;
  // sweep 1: histogram of local dst (key dword only; lines get L2-warm here)
  for (int blk = grp; blk < BIN_BLOCKS; blk += 64){
    int n = counts[blk*NBUCK + b];
    const unsigned int* segx = (const unsigned int*)(stg + ((size_t)blk*NBUCK + b)*CAP);
    for (int j = gl; j < n; j += 8){
      unsigned int rx = segx[2*j];
      atomicAdd(&hist[rx & 127], 1);
    }
  }
  __syncthreads();

  // exclusive scan of hist[128] (2 waves)
  int v = 0, inc = 0;
  if (tid < 128){
    v = hist[tid];
    inc = v;
    #pragma unroll
    for (int off = 1; off < 64; off <<= 1){
      int t = __shfl_up(inc, off);
      if (lane >= off) inc += t;
    }
    if (lane == 63) wtot[w] = inc;
  }
  __syncthreads();
  if (tid == 0){ int t0 = wtot[0]; wtot[0] = 0; wtot[1] = t0; }
  __syncthreads();
  if (tid < 128){
    int excl = wtot[w] + inc - v;
    start[tid] = excl;
    cur[tid] = excl;
  }
  __syncthreads();

  // sweep 2: direct sorted placement (stg re-read hits L2)
  for (int blk = grp; blk < BIN_BLOCKS; blk += 64){
    int n = counts[blk*NBUCK + b];
    const uint2* seg = stg + ((size_t)blk*NBUCK + b)*CAP;
    for (int j = gl; j < n; j += 8){
      uint2 r = seg[j];
      int pos = atomicAdd(&cur[r.x & 127], 1);
      if (pos < LCAP) lsev[pos] = make_uint2(r.x >> 7, r.y);
    }
  }
  __syncthreads();

  // aggregate: wave w handles local nodes w*16 .. w*16+15; 16 edges in flight.
  int g  = lane >> 4;
  int c4 = lane & 15;
  int h  = (c4 >= 8);
  float b0v = bias[c4*4 + 0], b1v = bias[c4*4 + 1], b2v = bias[c4*4 + 2], b3v = bias[c4*4 + 3];
  int f0 = (c4 & 7)*4;
  int wo = (h ? 32 : 0) + f0;   // lanes c4<8 compute MLP row 0 (s1), c4>=8 row 1 (s2)
  float m0 = wcomb[wo], m1 = wcomb[wo+1], m2 = wcomb[wo+2], m3 = wcomb[wo+3];
  for (int i = 0; i < 16; ++i){
    int nl = w*16 + i;
    int node = (b << 7) + nl;
    if (node >= N_NODES) break;
    int s0 = start[nl];
    int e0 = cur[nl]; if (e0 > LCAP) e0 = LCAP;
    int deg = e0 - s0; if (deg < 0) deg = 0;

    float a0=0.f, a1=0.f, a2=0.f, a3=0.f, dn=0.f;
    for (int j0 = 0; j0 < deg; j0 += 16){
      int jA = j0 + g, jB = j0 + 4 + g, jC = j0 + 8 + g, jD = j0 + 12 + g;
      float alA=0.f, alB=0.f, alC=0.f, alD=0.f;
      int snA=0, snB=0, snC=0, snD=0;
      if (jA < deg){ uint2 r = lsev[s0+jA]; snA = r.x;
        float2 e = __half22float2(*(const __half2*)&r.y); alA = (h?e.y:e.x); }
      if (jB < deg){ uint2 r = lsev[s0+jB]; snB = r.x;
        float2 e = __half22float2(*(const __half2*)&r.y); alB = (h?e.y:e.x); }
      if (jC < deg){ uint2 r = lsev[s0+jC]; snC = r.x;
        float2 e = __half22float2(*(const __half2*)&r.y); alC = (h?e.y:e.x); }
      if (jD < deg){ uint2 r = lsev[s0+jD]; snD = r.x;
        float2 e = __half22float2(*(const __half2*)&r.y); alD = (h?e.y:e.x); }
      dn += alA + alB + alC + alD;
      uint2 vA = *(const uint2*)(feat16 + (size_t)snA*HO + c4*4);
      uint2 vB = *(const uint2*)(feat16 + (size_t)snB*HO + c4*4);
      uint2 vC = *(const uint2*)(feat16 + (size_t)snC*HO + c4*4);
      uint2 vD = *(const uint2*)(feat16 + (size_t)snD*HO + c4*4);
      float2 fA01 = __half22float2(*(const __half2*)&vA.x);
      float2 fA23 = __half22float2(*(const __half2*)&vA.y);
      float2 fB01 = __half22float2(*(const __half2*)&vB.x);
      float2 fB23 = __half22float2(*(const __half2*)&vB.y);
      float2 fC01 = __half22float2(*(const __half2*)&vC.x);
      float2 fC23 = __half22float2(*(const __half2*)&vC.y);
      float2 fD01 = __half22float2(*(const __half2*)&vD.x);
      float2 fD23 = __half22float2(*(const __half2*)&vD.y);
      a0 = fmaf(alA, fA01.x, a0); a0 = fmaf(alB, fB01.x, a0);
      a0 = fmaf(alC, fC01.x, a0); a0 = fmaf(alD, fD01.x, a0);
      a1 = fmaf(alA, fA01.y, a1); a1 = fmaf(alB, fB01.y, a1);
      a1 = fmaf(alC, fC01.y, a1); a1 = fmaf(alD, fD01.y, a1);
      a2 = fmaf(alA, fA23.x, a2); a2 = fmaf(alB, fB23.x, a2);
      a2 = fmaf(alC, fC23.x, a2); a2 = fmaf(alD, fD23.x, a2);
      a3 = fmaf(alA, fA23.y, a3); a3 = fmaf(alB, fB23.y, a3);
      a3 = fmaf(alC, fC23.y, a3); a3 = fmaf(alD, fD23.y, a3);
    }
    a0 += __shfl_xor(a0, 16); a1 += __shfl_xor(a1, 16);
    a2 += __shfl_xor(a2, 16); a3 += __shfl_xor(a3, 16);
    dn += __shfl_xor(dn, 16);
    a0 += __shfl_xor(a0, 32); a1 += __shfl_xor(a1, 32);
    a2 += __shfl_xor(a2, 32); a3 += __shfl_xor(a3, 32);
    dn += __shfl_xor(dn, 32);
    float rh = dn > 0.f ? 1.f/dn : 0.f;   // deferred softmax divide
    a0 = fmaf(a0, rh, b0v); a1 = fmaf(a1, rh, b1v);
    a2 = fmaf(a2, rh, b2v); a3 = fmaf(a3, rh, b3v);
    float h0 = 0.5f*(a0 + __shfl_xor(a0, 8)); h0 = fmaxf(h0, 0.f);
    float h1 = 0.5f*(a1 + __shfl_xor(a1, 8)); h1 = fmaxf(h1, 0.f);
    float h2 = 0.5f*(a2 + __shfl_xor(a2, 8)); h2 = fmaxf(h2, 0.f);
    float h3 = 0.5f*(a3 + __shfl_xor(a3, 8)); h3 = fmaxf(h3, 0.f);
    float r = h0*m0 + h1*m1 + h2*m2 + h3*m3;
    r += __shfl_xor(r, 4); r += __shfl_xor(r, 2); r += __shfl_xor(r, 1);
    if (lane == 0)      s1[node] = r;
    else if (lane == 8) s2[node] = r;
  }
}

__global__ void edge_score_k(const int* __restrict__ src, const int* __restrict__ dst,
                             const float* __restrict__ s1, const float* __restrict__ s2,
                             const float* __restrict__ ccomb, float* __restrict__ out){
  int i = blockIdx.x*blockDim.x + threadIdx.x;
  if (i >= N_EDGES/4) return;
  int4 s4 = ((const int4*)src)[i];
  int4 d4 = ((const int4*)dst)[i];
  float c = ccomb[0];
  float4 o;
  o.x = s1[s4.x] + s2[d4.x] + c;
  o.y = s1[s4.y] + s2[d4.y] + c;
  o.z = s1[s4.z] + s2[d4.z] + c;
  o.w = s1[s4.w] + s2[d4.w] + c;
  ((float4*)out)[i] = o;
}

extern "C" void kernel_launch(void* const* d_in, const int* in_sizes, int n_in,
                              void* d_out, int out_size, void* d_ws, size_t ws_size,
                              hipStream_t stream){
  const float* x      = (const float*)d_in[0];
  const float* W      = (const float*)d_in[1];
  const float* attn_l = (const float*)d_in[2];
  const float* attn_r = (const float*)d_in[3];
  const float* bias   = (const float*)d_in[4];
  const float* W1     = (const float*)d_in[5];
  const float* b1     = (const float*)d_in[6];
  const float* W2     = (const float*)d_in[7];
  const float* b2     = (const float*)d_in[8];
  const int*   src    = (const int*)d_in[9];
  const int*   dst    = (const int*)d_in[10];
  float* out = (float*)d_out;

  float* ws = (float*)d_ws;
  size_t off = 0;
  __half* feat16 = (__half*)(ws + off); off += (size_t)N_NODES*HO/2;
  float*  el     = ws + off; off += (size_t)N_NODES*HEADS;
  float*  er     = ws + off; off += (size_t)N_NODES*HEADS;
  float*  s1     = ws + off; off += N_NODES;
  float*  s2     = ws + off; off += N_NODES;
  float*  wcomb  = ws + off; off += 64;
  float*  ccomb  = ws + off; off += 64;
  _Float16* Wt16 = (_Float16*)(ws + off); off += (size_t)HO*IN_F/2;  // 16 KB, 8B-aligned
  int*    counts = (int*)(ws + off); off += (size_t)BIN_BLOCKS*NBUCK;
  off = (off + 1) & ~(size_t)1;  // 8B align
  uint2*  stg    = (uint2*)(ws + off); off += (size_t)2*BIN_BLOCKS*NBUCK*CAP;

  wprep_k<<<1, 256, 0, stream>>>(W, W1, b1, W2, b2, Wt16, wcomb, ccomb);
  feat_k<<<(N_NODES + 63)/64, 256, 0, stream>>>(x, Wt16, attn_l, attn_r, feat16, el, er);
  bin_k<<<BIN_BLOCKS, BIN_THREADS, 0, stream>>>(src, dst, el, er, counts, stg);
  scatter_agg_k<<<NBUCK, 512, 0, stream>>>(counts, stg, feat16, bias, wcomb, s1, s2);
  edge_score_k<<<(N_EDGES/4 + 255)/256, 256, 0, stream>>>(src, dst, s1, s2, ccomb, out);
}